// Round 1
// baseline (3408.116 us; speedup 1.0000x reference)
//
#include <hip/hip_runtime.h>

// NeRF coarse renderer, fused single kernel, f32 baseline.
// Layout of d_in (setup_inputs order):
//  0 near (B,1)  1 far (B,1)  2 center (B,3)  3 direction (B,3)
//  4 W1 (3,256)  5 b1 (256)   6 W2 (256,256)  7 b2 (256)
//  8 W3 (256,4)  9 b3 (4)
// d_out: [rgb (B,3) | depth (B) | weights (B,64) | sigmas_last (B)]  f32

constexpr int KS = 64;    // samples per ray
constexpr int H  = 256;   // hidden width

__launch_bounds__(256, 2)
__global__ void nerf_fused_kernel(
    const float* __restrict__ g_near, const float* __restrict__ g_far,
    const float* __restrict__ g_center, const float* __restrict__ g_dir,
    const float* __restrict__ W1, const float* __restrict__ b1,
    const float* __restrict__ W2, const float* __restrict__ b2,
    const float* __restrict__ W3, const float* __restrict__ b3,
    float* __restrict__ out, int B)
{
    // h1: 64 points x 256 hidden, f32, 16B-chunk XOR swizzle (c ^ (lane&7))
    // so per-lane ds_read_b128 of row `lane` at uniform chunk is conflict-free.
    __shared__ __align__(16) float h1[KS * H];        // 64 KiB
    __shared__ __align__(16) float comb[4][KS][4];    //  4 KiB

    const int t    = threadIdx.x;
    const int lane = t & 63;
    const int wv   = __builtin_amdgcn_readfirstlane(t >> 6);  // wave id, provably uniform
    const int r    = blockIdx.x;

    // ---- ray parameters (uniform within block) ----
    const float nr = g_near[r];
    const float fa = g_far[r];
    const float cx = g_center[r*3+0], cy = g_center[r*3+1], cz = g_center[r*3+2];
    const float dx = g_dir[r*3+0],    dy = g_dir[r*3+1],    dz = g_dir[r*3+2];

    // ---- this thread's sample (one per lane) ----
    const float u  = (float)lane * (1.0f/63.0f);
    const float z  = nr * (1.0f - u) + fa * u;
    const float px = cx + z*dx, py = cy + z*dy, pz = cz + z*dz;

    // ---- layer 1: h1[lane][k0..k0+63], wave wv covers k-range wv*64 ----
    {
        const int k0 = wv * 64;
        #pragma unroll
        for (int kk = 0; kk < 16; ++kk) {
            const int k = k0 + kk*4;
            const float4 wa = *(const float4*)&W1[0*H + k];
            const float4 wb = *(const float4*)&W1[1*H + k];
            const float4 wc = *(const float4*)&W1[2*H + k];
            const float4 bb = *(const float4*)&b1[k];
            float4 h;
            h.x = fmaxf(fmaf(px, wa.x, fmaf(py, wb.x, fmaf(pz, wc.x, bb.x))), 0.0f);
            h.y = fmaxf(fmaf(px, wa.y, fmaf(py, wb.y, fmaf(pz, wc.y, bb.y))), 0.0f);
            h.z = fmaxf(fmaf(px, wa.z, fmaf(py, wb.z, fmaf(pz, wc.z, bb.z))), 0.0f);
            h.w = fmaxf(fmaf(px, wa.w, fmaf(py, wb.w, fmaf(pz, wc.w, bb.w))), 0.0f);
            const int c  = k >> 2;                 // logical 16B chunk 0..63
            const int pc = c ^ (lane & 7);         // swizzled chunk (bijective)
            *(float4*)&h1[lane*H + pc*4] = h;
        }
    }
    __syncthreads();

    // ---- layer 2 (256x256) + fused layer 3 partials ----
    // thread: point = lane, hidden-out range = [wv*64, wv*64+64), 4-wide j blocks.
    float o0 = 0.f, o1 = 0.f, o2 = 0.f, o3 = 0.f;   // partial out[4] over this wave's j
    const float* h1row = &h1[lane*H];
    const int swz = (lane & 7) * 4;

    #pragma unroll 1
    for (int jb = 0; jb < 16; ++jb) {
        const int j0 = wv*64 + jb*4;
        float4 a = *(const float4*)&b2[j0];
        #pragma unroll 4
        for (int kc = 0; kc < 64; ++kc) {
            const float4 hh = *(const float4*)&h1row[(kc*4) ^ swz];
            const float* wrow = &W2[(kc*4)*H + j0];         // uniform -> s_load
            const float4 w0 = *(const float4*)&wrow[0*H];
            const float4 w1 = *(const float4*)&wrow[1*H];
            const float4 w2 = *(const float4*)&wrow[2*H];
            const float4 w3 = *(const float4*)&wrow[3*H];
            a.x = fmaf(hh.x,w0.x, fmaf(hh.y,w1.x, fmaf(hh.z,w2.x, fmaf(hh.w,w3.x, a.x))));
            a.y = fmaf(hh.x,w0.y, fmaf(hh.y,w1.y, fmaf(hh.z,w2.y, fmaf(hh.w,w3.y, a.y))));
            a.z = fmaf(hh.x,w0.z, fmaf(hh.y,w1.z, fmaf(hh.z,w2.z, fmaf(hh.w,w3.z, a.z))));
            a.w = fmaf(hh.x,w0.w, fmaf(hh.y,w1.w, fmaf(hh.z,w2.w, fmaf(hh.w,w3.w, a.w))));
        }
        // relu(h2) then fused layer-3 partial accumulation
        a.x = fmaxf(a.x, 0.f); a.y = fmaxf(a.y, 0.f);
        a.z = fmaxf(a.z, 0.f); a.w = fmaxf(a.w, 0.f);
        const float4 c0 = *(const float4*)&W3[(j0+0)*4];
        const float4 c1 = *(const float4*)&W3[(j0+1)*4];
        const float4 c2 = *(const float4*)&W3[(j0+2)*4];
        const float4 c3 = *(const float4*)&W3[(j0+3)*4];
        o0 = fmaf(a.x,c0.x, fmaf(a.y,c1.x, fmaf(a.z,c2.x, fmaf(a.w,c3.x, o0))));
        o1 = fmaf(a.x,c0.y, fmaf(a.y,c1.y, fmaf(a.z,c2.y, fmaf(a.w,c3.y, o1))));
        o2 = fmaf(a.x,c0.z, fmaf(a.y,c1.z, fmaf(a.z,c2.z, fmaf(a.w,c3.z, o2))));
        o3 = fmaf(a.x,c0.w, fmaf(a.y,c1.w, fmaf(a.z,c2.w, fmaf(a.w,c3.w, o3))));
    }
    *(float4*)&comb[wv][lane][0] = make_float4(o0, o1, o2, o3);
    __syncthreads();

    // ---- volume rendering: wave 0, lane = sample ----
    if (t < 64) {
        float4 o = make_float4(0.f, 0.f, 0.f, 0.f);
        #pragma unroll
        for (int w = 0; w < 4; ++w) {
            const float4 c = *(const float4*)&comb[w][t][0];
            o.x += c.x; o.y += c.y; o.z += c.z; o.w += c.w;
        }
        o.x += b3[0]; o.y += b3[1]; o.z += b3[2]; o.w += b3[3];
        const float sigma = o.w;                 // raw (sigmas_last uses raw value)

        // delta_s = z_{s+1} - z_s, last = 1e10
        float delta;
        if (t == 63) {
            delta = 1e10f;
        } else {
            const float u2 = (float)(t + 1) * (1.0f/63.0f);
            delta = (nr * (1.0f - u2) + fa * u2) - z;
        }
        const float alpha = 1.0f - __expf(-delta * fmaxf(sigma, 0.0f));

        // exclusive product scan of (1 - alpha + eps) across 64 lanes
        float P = 1.0f - alpha + 1e-8f;
        #pragma unroll
        for (int off = 1; off < 64; off <<= 1) {
            const float v = __shfl_up(P, off, 64);
            if (t >= off) P *= v;
        }
        float T = __shfl_up(P, 1, 64);
        if (t == 0) T = 1.0f;
        const float w = alpha * T;

        out[(size_t)B*4 + (size_t)r*64 + t] = w;   // weights (B,64)

        // reductions across the ray
        float ws = w, dep = w * z, r0 = w * o.x, r1 = w * o.y, r2 = w * o.z;
        #pragma unroll
        for (int off = 32; off > 0; off >>= 1) {
            ws  += __shfl_xor(ws,  off, 64);
            dep += __shfl_xor(dep, off, 64);
            r0  += __shfl_xor(r0,  off, 64);
            r1  += __shfl_xor(r1,  off, 64);
            r2  += __shfl_xor(r2,  off, 64);
        }
        const float sl = __shfl(sigma, 63, 64);
        if (t == 0) {
            out[(size_t)r*3 + 0] = r0 + 1.0f - ws;
            out[(size_t)r*3 + 1] = r1 + 1.0f - ws;
            out[(size_t)r*3 + 2] = r2 + 1.0f - ws;
            out[(size_t)B*3 + r] = dep;            // depth
            out[(size_t)B*68 + r] = sl;            // sigmas_last
        }
    }
}

extern "C" void kernel_launch(void* const* d_in, const int* in_sizes, int n_in,
                              void* d_out, int out_size, void* d_ws, size_t ws_size,
                              hipStream_t stream)
{
    const int B = in_sizes[0];   // near is (B,1)
    nerf_fused_kernel<<<B, 256, 0, stream>>>(
        (const float*)d_in[0], (const float*)d_in[1],
        (const float*)d_in[2], (const float*)d_in[3],
        (const float*)d_in[4], (const float*)d_in[5],
        (const float*)d_in[6], (const float*)d_in[7],
        (const float*)d_in[8], (const float*)d_in[9],
        (float*)d_out, B);
}

// Round 3
// 489.556 us; speedup vs baseline: 6.9616x; 6.9616x over previous
//
#include <hip/hip_runtime.h>
#include <hip/hip_bf16.h>

// NeRF coarse renderer: bf16 MFMA (hi/lo split => ~f32 accuracy) for layer 2,
// f32 VALU for layers 1 & 3 + volume rendering. 2 rays per block.
//
// d_in: 0 near(B,1) 1 far(B,1) 2 center(B,3) 3 dir(B,3)
//       4 W1(3,256) 5 b1(256) 6 W2(256,256) 7 b2(256) 8 W3(256,4) 9 b3(4)
// d_out: [rgb (B,3) | depth (B) | weights (B,64) | sigmas_last (B)] f32
// d_ws: W2 repacked as MFMA B-fragments, bf16 hi[64K] + lo[64K] (256 KiB).

constexpr int H   = 256;
constexpr int KS  = 64;     // samples per ray
constexpr int RPB = 2;      // rays per block
constexpr int MR  = 128;    // rows per block = KS*RPB

typedef __attribute__((ext_vector_type(8))) short short8;  // 8 bf16 (A/B frag)
typedef __attribute__((ext_vector_type(4))) float f32x4;   // C/D frag

__device__ __forceinline__ f32x4 mfma16(short8 a, short8 b, f32x4 c) {
    return __builtin_amdgcn_mfma_f32_16x16x32_bf16(a, b, c, 0, 0, 0);
}
__device__ __forceinline__ void split_bf16(float x, short& hi, short& lo) {
    __hip_bfloat16 h = __float2bfloat16(x);
    float hf = __bfloat162float(h);
    __hip_bfloat16 l = __float2bfloat16(x - hf);
    union { __hip_bfloat16 b; short s; } c1, c2;
    c1.b = h; c2.b = l;
    hi = c1.s; lo = c2.s;
}

// ---- pre-pass: pack W2 (f32 row-major [k][n]) into frag-ordered bf16 hi/lo.
// Element i = ((ks*16 + ntg)*64 + lane)*8 + e  maps to
//   k = ks*32 + (lane>>4)*8 + e,  n = ntg*16 + (lane&15).
__global__ void pack_w2_kernel(const float* __restrict__ W2,
                               unsigned short* __restrict__ hi,
                               unsigned short* __restrict__ lo)
{
    const int i  = blockIdx.x * 256 + threadIdx.x;   // 0..65535
    const int e  = i & 7;
    const int l  = (i >> 3) & 63;
    const int nt = (i >> 9) & 15;
    const int ks = i >> 13;
    const int k  = ks * 32 + (l >> 4) * 8 + e;
    const int n  = nt * 16 + (l & 15);
    short h, lw;
    split_bf16(W2[k * H + n], h, lw);
    hi[i] = (unsigned short)h;
    lo[i] = (unsigned short)lw;
}

struct ABfrags { unsigned short hi[8 * 8 * 64 * 8]; unsigned short lo[8 * 8 * 64 * 8]; };
union StageU { ABfrags ab; float h2T[H * 132]; };   // A frags (128KiB) | h2^T padded (132KiB)

__launch_bounds__(512, 1)
__global__ void nerf_mfma_kernel(
    const float* __restrict__ g_near, const float* __restrict__ g_far,
    const float* __restrict__ g_center, const float* __restrict__ g_dir,
    const float* __restrict__ W1, const float* __restrict__ b1,
    const float* __restrict__ b2,
    const float* __restrict__ W3, const float* __restrict__ b3,
    const unsigned short* __restrict__ w2h, const unsigned short* __restrict__ w2l,
    float* __restrict__ out, int B)
{
    __shared__ __align__(16) StageU u;
    __shared__ __align__(16) float pts[MR][4];      // (px,py,pz,z)
    __shared__ __align__(16) float comb[4][MR][4];  // layer-3 partials (j-quarters)

    const int t    = threadIdx.x;
    const int lane = t & 63;
    const int wv   = __builtin_amdgcn_readfirstlane(t >> 6);   // 0..7
    const int r0   = blockIdx.x * RPB;

    // ---- phase 0: sample points ----
    if (t < MR) {
        const int ri = t >> 6, s = t & 63;
        const int rr = min(r0 + ri, B - 1);
        const float nr = g_near[rr], fa = g_far[rr];
        const float uu = (float)s * (1.0f / 63.0f);
        const float z  = nr * (1.0f - uu) + fa * uu;
        pts[t][0] = g_center[rr*3+0] + z * g_dir[rr*3+0];
        pts[t][1] = g_center[rr*3+1] + z * g_dir[rr*3+1];
        pts[t][2] = g_center[rr*3+2] + z * g_dir[rr*3+2];
        pts[t][3] = z;
    }
    __syncthreads();

    // ---- phase 1: layer 1 (f32), written directly as A-fragments (hi/lo) ----
    // wave wv owns k-step ks=wv; thread = frag-lane `lane`; loop over M-tiles.
    {
        const int ksi   = wv;
        const int kbase = ksi * 32 + (lane >> 4) * 8;   // 8 consecutive k
        float w1r[3][8], b1r[8];
        #pragma unroll
        for (int c = 0; c < 3; ++c) {
            const f32x4 a = *(const f32x4*)&W1[c * H + kbase];
            const f32x4 b = *(const f32x4*)&W1[c * H + kbase + 4];
            #pragma unroll
            for (int e = 0; e < 4; ++e) { w1r[c][e] = a[e]; w1r[c][e+4] = b[e]; }
        }
        {
            const f32x4 a = *(const f32x4*)&b1[kbase];
            const f32x4 b = *(const f32x4*)&b1[kbase + 4];
            #pragma unroll
            for (int e = 0; e < 4; ++e) { b1r[e] = a[e]; b1r[e+4] = b[e]; }
        }
        const int prow = lane & 15;
        #pragma unroll
        for (int mt = 0; mt < 8; ++mt) {
            const f32x4 pt = *(const f32x4*)&pts[mt * 16 + prow][0];
            short8 hv, lv;
            #pragma unroll
            for (int e = 0; e < 8; ++e) {
                float x = fmaf(pt[0], w1r[0][e],
                          fmaf(pt[1], w1r[1][e],
                          fmaf(pt[2], w1r[2][e], b1r[e])));
                x = fmaxf(x, 0.0f);
                short h, lw; split_bf16(x, h, lw);
                hv[e] = h; lv[e] = lw;
            }
            const int idx = ((ksi * 8 + mt) * 64 + lane) * 8;
            *(short8*)&u.ab.hi[idx] = hv;
            *(short8*)&u.ab.lo[idx] = lv;
        }
    }
    __syncthreads();

    // ---- phase 2: layer 2 GEMM via MFMA, 3-term hi/lo split ----
    f32x4 acc[8][2];
    #pragma unroll
    for (int mt = 0; mt < 8; ++mt) {
        acc[mt][0] = (f32x4){0.f,0.f,0.f,0.f};
        acc[mt][1] = (f32x4){0.f,0.f,0.f,0.f};
    }
    {
        const int ntg0 = wv * 2, ntg1 = ntg0 + 1;
        const short8* Bh = (const short8*)w2h;
        const short8* Bl = (const short8*)w2l;
        const short8* Ah = (const short8*)u.ab.hi;
        const short8* Al = (const short8*)u.ab.lo;
        #pragma unroll 1
        for (int ks = 0; ks < 8; ++ks) {
            const short8 b0h = Bh[(ks * 16 + ntg0) * 64 + lane];
            const short8 b0l = Bl[(ks * 16 + ntg0) * 64 + lane];
            const short8 b1h_ = Bh[(ks * 16 + ntg1) * 64 + lane];
            const short8 b1l_ = Bl[(ks * 16 + ntg1) * 64 + lane];
            #pragma unroll
            for (int mt = 0; mt < 8; ++mt) {
                const short8 ah = Ah[(ks * 8 + mt) * 64 + lane];
                const short8 al = Al[(ks * 8 + mt) * 64 + lane];
                f32x4 c0 = acc[mt][0], c1 = acc[mt][1];
                c0 = mfma16(ah, b0h, c0);
                c0 = mfma16(al, b0h, c0);
                c0 = mfma16(ah, b0l, c0);
                c1 = mfma16(ah, b1h_, c1);
                c1 = mfma16(al, b1h_, c1);
                c1 = mfma16(ah, b1l_, c1);
                acc[mt][0] = c0; acc[mt][1] = c1;
            }
        }
    }
    __syncthreads();   // A-frag region dead; safe to overwrite with h2T

    // ---- phase 3: +b2, ReLU, store h2 transposed [col][row] (pad 132) ----
    {
        const int ntg0 = wv * 2, ntg1 = ntg0 + 1;
        const int c0 = ntg0 * 16 + (lane & 15);
        const int c1 = ntg1 * 16 + (lane & 15);
        const float b2c0 = b2[c0], b2c1 = b2[c1];
        const int row0b = (lane >> 4) * 4;
        #pragma unroll
        for (int mt = 0; mt < 8; ++mt) {
            const int row0 = mt * 16 + row0b;
            f32x4 v0 = acc[mt][0], v1 = acc[mt][1];
            #pragma unroll
            for (int q = 0; q < 4; ++q) {
                v0[q] = fmaxf(v0[q] + b2c0, 0.0f);
                v1[q] = fmaxf(v1[q] + b2c1, 0.0f);
            }
            *(f32x4*)&u.h2T[c0 * 132 + row0] = v0;
            *(f32x4*)&u.h2T[c1 * 132 + row0] = v1;
        }
    }
    __syncthreads();

    // ---- phase 4: layer 3 (f32 VALU), j split in QUARTERS across all 512 thr ----
    // hh in [0,4): j-range [hh*64, hh*64+64). No OOB: comb is [4][128][4].
    {
        const int p  = t & 127;
        const int hh = t >> 7;                    // 0..3, all threads legitimate
        f32x4 o = (f32x4){0.f,0.f,0.f,0.f};
        #pragma unroll 4
        for (int jj = 0; jj < 64; ++jj) {
            const int j = hh * 64 + jj;
            const float hv = u.h2T[j * 132 + p];
            const f32x4 w3 = *(const f32x4*)&W3[j * 4];
            o[0] = fmaf(hv, w3[0], o[0]);
            o[1] = fmaf(hv, w3[1], o[1]);
            o[2] = fmaf(hv, w3[2], o[2]);
            o[3] = fmaf(hv, w3[3], o[3]);
        }
        *(f32x4*)&comb[hh][p][0] = o;
    }
    __syncthreads();

    // ---- phase 5: volume rendering (waves 0,1 = rays 0,1) ----
    if (t < 128) {
        const int ri = t >> 6, s = t & 63;
        const int r = r0 + ri;
        if (r < B) {
            const f32x4 pa = *(const f32x4*)&comb[0][t][0];
            const f32x4 pb = *(const f32x4*)&comb[1][t][0];
            const f32x4 pc = *(const f32x4*)&comb[2][t][0];
            const f32x4 pd = *(const f32x4*)&comb[3][t][0];
            const float o0 = pa[0] + pb[0] + pc[0] + pd[0] + b3[0];
            const float o1 = pa[1] + pb[1] + pc[1] + pd[1] + b3[1];
            const float o2 = pa[2] + pb[2] + pc[2] + pd[2] + b3[2];
            const float sigma = pa[3] + pb[3] + pc[3] + pd[3] + b3[3];

            const float z  = pts[t][3];
            const float zn = __shfl_down(z, 1, 64);
            const float delta = (s == 63) ? 1e10f : (zn - z);
            const float alpha = 1.0f - __expf(-delta * fmaxf(sigma, 0.0f));

            // exclusive product scan of (1 - alpha + eps)
            float P = 1.0f - alpha + 1e-8f;
            #pragma unroll
            for (int off = 1; off < 64; off <<= 1) {
                const float v = __shfl_up(P, off, 64);
                if (s >= off) P *= v;
            }
            float T = __shfl_up(P, 1, 64);
            if (s == 0) T = 1.0f;
            const float w = alpha * T;

            out[(size_t)B * 4 + (size_t)r * 64 + s] = w;

            float ws = w, dep = w * z, q0 = w * o0, q1 = w * o1, q2 = w * o2;
            #pragma unroll
            for (int off = 32; off > 0; off >>= 1) {
                ws  += __shfl_xor(ws,  off, 64);
                dep += __shfl_xor(dep, off, 64);
                q0  += __shfl_xor(q0,  off, 64);
                q1  += __shfl_xor(q1,  off, 64);
                q2  += __shfl_xor(q2,  off, 64);
            }
            const float sl = __shfl(sigma, 63, 64);
            if (s == 0) {
                out[(size_t)r * 3 + 0] = q0 + 1.0f - ws;
                out[(size_t)r * 3 + 1] = q1 + 1.0f - ws;
                out[(size_t)r * 3 + 2] = q2 + 1.0f - ws;
                out[(size_t)B * 3 + r] = dep;
                out[(size_t)B * 68 + r] = sl;
            }
        }
    }
}

extern "C" void kernel_launch(void* const* d_in, const int* in_sizes, int n_in,
                              void* d_out, int out_size, void* d_ws, size_t ws_size,
                              hipStream_t stream)
{
    const int B = in_sizes[0];
    if (ws_size < (size_t)(2 * 65536 * sizeof(unsigned short))) return;  // need 256 KiB

    unsigned short* w2h = (unsigned short*)d_ws;
    unsigned short* w2l = w2h + 65536;

    pack_w2_kernel<<<256, 256, 0, stream>>>((const float*)d_in[6], w2h, w2l);

    const int grid = (B + RPB - 1) / RPB;
    nerf_mfma_kernel<<<grid, 512, 0, stream>>>(
        (const float*)d_in[0], (const float*)d_in[1],
        (const float*)d_in[2], (const float*)d_in[3],
        (const float*)d_in[4], (const float*)d_in[5],
        (const float*)d_in[7],
        (const float*)d_in[8], (const float*)d_in[9],
        w2h, w2l,
        (float*)d_out, B);
}

// Round 4
// 412.098 us; speedup vs baseline: 8.2702x; 1.1880x over previous
//
#include <hip/hip_runtime.h>
#include <hip/hip_bf16.h>

// NeRF coarse renderer: bf16 MFMA (3-term hi/lo split => ~f32 accuracy) for
// layer 2, f32 VALU for layers 1 & 3 + volume rendering.
// 1 ray per block (M=64), LDS ~77 KiB => 2 blocks/CU so block A's MFMA phase
// overlaps block B's VALU phases (separate pipes, m114).
//
// d_in: 0 near(B,1) 1 far(B,1) 2 center(B,3) 3 dir(B,3)
//       4 W1(3,256) 5 b1(256) 6 W2(256,256) 7 b2(256) 8 W3(256,4) 9 b3(4)
// d_out: [rgb (B,3) | depth (B) | weights (B,64) | sigmas_last (B)] f32
// d_ws: W2 repacked as MFMA B-fragments, bf16 hi[64K] + lo[64K] (256 KiB).

constexpr int H  = 256;
constexpr int KS = 64;     // samples per ray = M rows per block

typedef __attribute__((ext_vector_type(8))) short short8;  // 8 bf16 (A/B frag)
typedef __attribute__((ext_vector_type(4))) float f32x4;   // C/D frag

__device__ __forceinline__ f32x4 mfma16(short8 a, short8 b, f32x4 c) {
    return __builtin_amdgcn_mfma_f32_16x16x32_bf16(a, b, c, 0, 0, 0);
}
__device__ __forceinline__ void split_bf16(float x, short& hi, short& lo) {
    __hip_bfloat16 h = __float2bfloat16(x);
    float hf = __bfloat162float(h);
    __hip_bfloat16 l = __float2bfloat16(x - hf);
    union { __hip_bfloat16 b; short s; } c1, c2;
    c1.b = h; c2.b = l;
    hi = c1.s; lo = c2.s;
}

// ---- pre-pass: pack W2 (f32 row-major [k][n]) into frag-ordered bf16 hi/lo.
// Element i = ((ks*16 + ntg)*64 + lane)*8 + e  maps to
//   k = ks*32 + (lane>>4)*8 + e,  n = ntg*16 + (lane&15).
__global__ void pack_w2_kernel(const float* __restrict__ W2,
                               unsigned short* __restrict__ hi,
                               unsigned short* __restrict__ lo)
{
    const int i  = blockIdx.x * 256 + threadIdx.x;   // 0..65535
    const int e  = i & 7;
    const int l  = (i >> 3) & 63;
    const int nt = (i >> 9) & 15;
    const int ks = i >> 13;
    const int k  = ks * 32 + (l >> 4) * 8 + e;
    const int n  = nt * 16 + (l & 15);
    short h, lw;
    split_bf16(W2[k * H + n], h, lw);
    hi[i] = (unsigned short)h;
    lo[i] = (unsigned short)lw;
}

// A-frags: 8 ks * 4 mt * 64 lanes * 8 elems, hi+lo  (64 KiB)
struct ABfrags { unsigned short hi[8 * 4 * 64 * 8]; unsigned short lo[8 * 4 * 64 * 8]; };
union StageU { ABfrags ab; float h2T[H * 68]; };   // union: 68 KiB

__launch_bounds__(512, 4)
__global__ void nerf_mfma_kernel(
    const float* __restrict__ g_near, const float* __restrict__ g_far,
    const float* __restrict__ g_center, const float* __restrict__ g_dir,
    const float* __restrict__ W1, const float* __restrict__ b1,
    const float* __restrict__ b2,
    const float* __restrict__ W3, const float* __restrict__ b3,
    const unsigned short* __restrict__ w2h, const unsigned short* __restrict__ w2l,
    float* __restrict__ out, int B)
{
    __shared__ __align__(16) StageU u;             // 68 KiB
    __shared__ __align__(16) float pts[KS][4];     //  1 KiB (px,py,pz,z)
    __shared__ __align__(16) float comb[8][KS][4]; //  8 KiB layer-3 partials

    const int t    = threadIdx.x;
    const int lane = t & 63;
    const int wv   = __builtin_amdgcn_readfirstlane(t >> 6);   // 0..7
    const int r    = blockIdx.x;                               // ray id

    // ---- phase 0: sample points ----
    if (t < KS) {
        const float nr = g_near[r], fa = g_far[r];
        const float uu = (float)t * (1.0f / 63.0f);
        const float z  = nr * (1.0f - uu) + fa * uu;
        pts[t][0] = g_center[r*3+0] + z * g_dir[r*3+0];
        pts[t][1] = g_center[r*3+1] + z * g_dir[r*3+1];
        pts[t][2] = g_center[r*3+2] + z * g_dir[r*3+2];
        pts[t][3] = z;
    }
    __syncthreads();

    // ---- phase 1: layer 1 (f32), written directly as A-fragments (hi/lo) ----
    // wave wv owns k-step ks=wv; lane = frag lane; 4 M-tiles of 16 rows.
    {
        const int ksi   = wv;
        const int kbase = ksi * 32 + (lane >> 4) * 8;   // 8 consecutive k
        float w1r[3][8], b1r[8];
        #pragma unroll
        for (int c = 0; c < 3; ++c) {
            const f32x4 a = *(const f32x4*)&W1[c * H + kbase];
            const f32x4 b = *(const f32x4*)&W1[c * H + kbase + 4];
            #pragma unroll
            for (int e = 0; e < 4; ++e) { w1r[c][e] = a[e]; w1r[c][e+4] = b[e]; }
        }
        {
            const f32x4 a = *(const f32x4*)&b1[kbase];
            const f32x4 b = *(const f32x4*)&b1[kbase + 4];
            #pragma unroll
            for (int e = 0; e < 4; ++e) { b1r[e] = a[e]; b1r[e+4] = b[e]; }
        }
        const int prow = lane & 15;
        #pragma unroll
        for (int mt = 0; mt < 4; ++mt) {
            const f32x4 pt = *(const f32x4*)&pts[mt * 16 + prow][0];
            short8 hv, lv;
            #pragma unroll
            for (int e = 0; e < 8; ++e) {
                float x = fmaf(pt[0], w1r[0][e],
                          fmaf(pt[1], w1r[1][e],
                          fmaf(pt[2], w1r[2][e], b1r[e])));
                x = fmaxf(x, 0.0f);
                short h, lw; split_bf16(x, h, lw);
                hv[e] = h; lv[e] = lw;
            }
            const int idx = ((ksi * 4 + mt) * 64 + lane) * 8;
            *(short8*)&u.ab.hi[idx] = hv;
            *(short8*)&u.ab.lo[idx] = lv;
        }
    }
    __syncthreads();

    // ---- phase 2: layer 2 GEMM via MFMA, 3-term hi/lo split ----
    f32x4 acc[4][2];
    #pragma unroll
    for (int mt = 0; mt < 4; ++mt) {
        acc[mt][0] = (f32x4){0.f,0.f,0.f,0.f};
        acc[mt][1] = (f32x4){0.f,0.f,0.f,0.f};
    }
    {
        const int ntg0 = wv * 2, ntg1 = ntg0 + 1;
        const short8* Bh = (const short8*)w2h;
        const short8* Bl = (const short8*)w2l;
        const short8* Ah = (const short8*)u.ab.hi;
        const short8* Al = (const short8*)u.ab.lo;
        __builtin_amdgcn_s_setprio(1);
        #pragma unroll 2
        for (int ks = 0; ks < 8; ++ks) {
            const short8 b0h  = Bh[(ks * 16 + ntg0) * 64 + lane];
            const short8 b0l  = Bl[(ks * 16 + ntg0) * 64 + lane];
            const short8 b1h_ = Bh[(ks * 16 + ntg1) * 64 + lane];
            const short8 b1l_ = Bl[(ks * 16 + ntg1) * 64 + lane];
            #pragma unroll
            for (int mt = 0; mt < 4; ++mt) {
                const short8 ah = Ah[(ks * 4 + mt) * 64 + lane];
                const short8 al = Al[(ks * 4 + mt) * 64 + lane];
                f32x4 c0 = acc[mt][0], c1 = acc[mt][1];
                c0 = mfma16(ah, b0h, c0);
                c0 = mfma16(al, b0h, c0);
                c0 = mfma16(ah, b0l, c0);
                c1 = mfma16(ah, b1h_, c1);
                c1 = mfma16(al, b1h_, c1);
                c1 = mfma16(ah, b1l_, c1);
                acc[mt][0] = c0; acc[mt][1] = c1;
            }
        }
        __builtin_amdgcn_s_setprio(0);
    }
    __syncthreads();   // A-frag region dead; safe to overwrite with h2T

    // ---- phase 3: +b2, ReLU, store h2 transposed [col][row] (pad 68) ----
    {
        const int ntg0 = wv * 2, ntg1 = ntg0 + 1;
        const int c0 = ntg0 * 16 + (lane & 15);
        const int c1 = ntg1 * 16 + (lane & 15);
        const float b2c0 = b2[c0], b2c1 = b2[c1];
        const int row0b = (lane >> 4) * 4;
        #pragma unroll
        for (int mt = 0; mt < 4; ++mt) {
            const int row0 = mt * 16 + row0b;
            f32x4 v0 = acc[mt][0], v1 = acc[mt][1];
            #pragma unroll
            for (int q = 0; q < 4; ++q) {
                v0[q] = fmaxf(v0[q] + b2c0, 0.0f);
                v1[q] = fmaxf(v1[q] + b2c1, 0.0f);
            }
            *(f32x4*)&u.h2T[c0 * 68 + row0] = v0;
            *(f32x4*)&u.h2T[c1 * 68 + row0] = v1;
        }
    }
    __syncthreads();

    // ---- phase 4: layer 3 (f32 VALU). 8 j-groups of 32; all 512 threads. ----
    {
        const int p  = t & 63;          // point (row)
        const int hh = t >> 6;          // j-group 0..7
        f32x4 o = (f32x4){0.f,0.f,0.f,0.f};
        #pragma unroll 4
        for (int jj = 0; jj < 32; ++jj) {
            const int j = hh * 32 + jj;
            const float hv = u.h2T[j * 68 + p];
            const f32x4 w3 = *(const f32x4*)&W3[j * 4];
            o[0] = fmaf(hv, w3[0], o[0]);
            o[1] = fmaf(hv, w3[1], o[1]);
            o[2] = fmaf(hv, w3[2], o[2]);
            o[3] = fmaf(hv, w3[3], o[3]);
        }
        *(f32x4*)&comb[hh][p][0] = o;
    }
    __syncthreads();

    // ---- phase 5: volume rendering (wave 0, lane = sample) ----
    if (t < KS) {
        const int s = t;
        f32x4 oo = (f32x4){0.f,0.f,0.f,0.f};
        #pragma unroll
        for (int q = 0; q < 8; ++q) {
            const f32x4 c = *(const f32x4*)&comb[q][s][0];
            oo[0] += c[0]; oo[1] += c[1]; oo[2] += c[2]; oo[3] += c[3];
        }
        const float o0 = oo[0] + b3[0];
        const float o1 = oo[1] + b3[1];
        const float o2 = oo[2] + b3[2];
        const float sigma = oo[3] + b3[3];

        const float z  = pts[s][3];
        const float zn = __shfl_down(z, 1, 64);
        const float delta = (s == 63) ? 1e10f : (zn - z);
        const float alpha = 1.0f - __expf(-delta * fmaxf(sigma, 0.0f));

        // exclusive product scan of (1 - alpha + eps)
        float P = 1.0f - alpha + 1e-8f;
        #pragma unroll
        for (int off = 1; off < 64; off <<= 1) {
            const float v = __shfl_up(P, off, 64);
            if (s >= off) P *= v;
        }
        float T = __shfl_up(P, 1, 64);
        if (s == 0) T = 1.0f;
        const float w = alpha * T;

        out[(size_t)B * 4 + (size_t)r * 64 + s] = w;

        float ws = w, dep = w * z, q0 = w * o0, q1 = w * o1, q2 = w * o2;
        #pragma unroll
        for (int off = 32; off > 0; off >>= 1) {
            ws  += __shfl_xor(ws,  off, 64);
            dep += __shfl_xor(dep, off, 64);
            q0  += __shfl_xor(q0,  off, 64);
            q1  += __shfl_xor(q1,  off, 64);
            q2  += __shfl_xor(q2,  off, 64);
        }
        const float sl = __shfl(sigma, 63, 64);
        if (s == 0) {
            out[(size_t)r * 3 + 0] = q0 + 1.0f - ws;
            out[(size_t)r * 3 + 1] = q1 + 1.0f - ws;
            out[(size_t)r * 3 + 2] = q2 + 1.0f - ws;
            out[(size_t)B * 3 + r] = dep;
            out[(size_t)B * 68 + r] = sl;
        }
    }
}

extern "C" void kernel_launch(void* const* d_in, const int* in_sizes, int n_in,
                              void* d_out, int out_size, void* d_ws, size_t ws_size,
                              hipStream_t stream)
{
    const int B = in_sizes[0];
    if (ws_size < (size_t)(2 * 65536 * sizeof(unsigned short))) return;  // need 256 KiB

    unsigned short* w2h = (unsigned short*)d_ws;
    unsigned short* w2l = w2h + 65536;

    pack_w2_kernel<<<256, 256, 0, stream>>>((const float*)d_in[6], w2h, w2l);

    nerf_mfma_kernel<<<B, 512, 0, stream>>>(
        (const float*)d_in[0], (const float*)d_in[1],
        (const float*)d_in[2], (const float*)d_in[3],
        (const float*)d_in[4], (const float*)d_in[5],
        (const float*)d_in[7],
        (const float*)d_in[8], (const float*)d_in[9],
        w2h, w2l,
        (float*)d_out, B);
}

// Round 7
// 323.199 us; speedup vs baseline: 10.5450x; 1.2751x over previous
//
#include <hip/hip_runtime.h>
#include <hip/hip_bf16.h>

// NeRF coarse renderer. Layer 2 on bf16 MFMA:
//   rows 0-47:  h2 = Ah*(Bh+Bl)          (2-term, err ~2^-9 — harmless, smooth path)
//   rows 48-63: h2 = Ah*(Bh+Bl) + Al*Bh  (3-term, err ~2^-18 — sample 63 feeds the
//                                         alpha = 1-exp(-1e10*relu(sigma)) STEP)
// sigma_63 additionally recomputed from an f32-staged post-relu h2 row 63.
// Layers 1&3 + volume rendering on f32 VALU. 1 ray/block, ~50 KiB LDS
// => 3 blocks/CU so MFMA and VALU phases of different blocks overlap.
//
// d_in: 0 near(B,1) 1 far(B,1) 2 center(B,3) 3 dir(B,3)
//       4 W1(3,256) 5 b1(256) 6 W2(256,256) 7 b2(256) 8 W3(256,4) 9 b3(4)
// d_out: [rgb (B,3) | depth (B) | weights (B,64) | sigmas_last (B)] f32
// d_ws: W2 repacked as MFMA B-fragments, bf16 hi[64K] + lo[64K] (256 KiB).

constexpr int H  = 256;
constexpr int KS = 64;     // samples per ray = M rows per block

typedef __attribute__((ext_vector_type(8))) short short8;           // 8 bf16
typedef __attribute__((ext_vector_type(4))) float f32x4;            // C/D frag
typedef __attribute__((ext_vector_type(4))) unsigned short bf16x4;  // 4 bf16

__device__ __forceinline__ f32x4 mfma16(short8 a, short8 b, f32x4 c) {
    return __builtin_amdgcn_mfma_f32_16x16x32_bf16(a, b, c, 0, 0, 0);
}
__device__ __forceinline__ void split_bf16(float x, short& hi, short& lo) {
    __hip_bfloat16 h = __float2bfloat16(x);
    float hf = __bfloat162float(h);
    __hip_bfloat16 l = __float2bfloat16(x - hf);
    union { __hip_bfloat16 b; short s; } c1, c2;
    c1.b = h; c2.b = l;
    hi = c1.s; lo = c2.s;
}
__device__ __forceinline__ unsigned short f2bf(float x) {
    union { __hip_bfloat16 b; unsigned short s; } c;
    c.b = __float2bfloat16(x);
    return c.s;
}
__device__ __forceinline__ float bf2f(unsigned short s) {
    union { unsigned int u; float f; } c;
    c.u = ((unsigned int)s) << 16;
    return c.f;
}

// ---- pre-pass: pack W2 (f32 row-major [k][n]) into frag-ordered bf16 hi/lo.
// Element i = ((ks*16 + ntg)*64 + lane)*8 + e  maps to
//   k = ks*32 + (lane>>4)*8 + e,  n = ntg*16 + (lane&15).
__global__ void pack_w2_kernel(const float* __restrict__ W2,
                               unsigned short* __restrict__ hi,
                               unsigned short* __restrict__ lo)
{
    const int i  = blockIdx.x * 256 + threadIdx.x;   // 0..65535
    const int e  = i & 7;
    const int l  = (i >> 3) & 63;
    const int nt = (i >> 9) & 15;
    const int ks = i >> 13;
    const int k  = ks * 32 + (l >> 4) * 8 + e;
    const int n  = nt * 16 + (l & 15);
    short h, lw;
    split_bf16(W2[k * H + n], h, lw);
    hi[i] = (unsigned short)h;
    lo[i] = (unsigned short)lw;
}

// Ah: 8 ks * 4 mt * 64 lanes * 8 = 32 KiB; Al (mt==3 only): 8 ks * 64 * 8 = 8 KiB
struct ABfrags {
    unsigned short ah[8 * 4 * 64 * 8];
    unsigned short al3[8 * 64 * 8];
};
// h2 transposed bf16 [col][row] stride 72 = 36 KiB. Union = 40 KiB.
union StageU { ABfrags ab; unsigned short h2T[H * 72]; };

__launch_bounds__(512, 6)
__global__ void nerf_mfma_kernel(
    const float* __restrict__ g_near, const float* __restrict__ g_far,
    const float* __restrict__ g_center, const float* __restrict__ g_dir,
    const float* __restrict__ W1, const float* __restrict__ b1,
    const float* __restrict__ b2,
    const float* __restrict__ W3, const float* __restrict__ b3,
    const unsigned short* __restrict__ w2h, const unsigned short* __restrict__ w2l,
    float* __restrict__ out, int B)
{
    __shared__ __align__(16) StageU u;             // 40 KiB
    __shared__ __align__(16) float pts[KS][4];     //  1 KiB (px,py,pz,z)
    __shared__ __align__(16) float comb[8][KS][4]; //  8 KiB layer-3 partials
    __shared__ __align__(16) float row63[H];       //  1 KiB post-relu f32 h2[63][:]

    const int t    = threadIdx.x;
    const int lane = t & 63;
    const int wv   = __builtin_amdgcn_readfirstlane(t >> 6);   // 0..7
    const int r    = blockIdx.x;                               // ray id

    // ---- phase 0: sample points ----
    if (t < KS) {
        const float nr = g_near[r], fa = g_far[r];
        const float uu = (float)t * (1.0f / 63.0f);
        const float z  = nr * (1.0f - uu) + fa * uu;
        pts[t][0] = g_center[r*3+0] + z * g_dir[r*3+0];
        pts[t][1] = g_center[r*3+1] + z * g_dir[r*3+1];
        pts[t][2] = g_center[r*3+2] + z * g_dir[r*3+2];
        pts[t][3] = z;
    }
    __syncthreads();

    // ---- phase 1: layer 1 (f32); h1 -> bf16 A-frags (hi; +lo for mt==3) ----
    {
        const int ksi   = wv;
        const int kbase = ksi * 32 + (lane >> 4) * 8;   // 8 consecutive k
        float w1r[3][8], b1r[8];
        #pragma unroll
        for (int c = 0; c < 3; ++c) {
            const f32x4 a = *(const f32x4*)&W1[c * H + kbase];
            const f32x4 b = *(const f32x4*)&W1[c * H + kbase + 4];
            #pragma unroll
            for (int e = 0; e < 4; ++e) { w1r[c][e] = a[e]; w1r[c][e+4] = b[e]; }
        }
        {
            const f32x4 a = *(const f32x4*)&b1[kbase];
            const f32x4 b = *(const f32x4*)&b1[kbase + 4];
            #pragma unroll
            for (int e = 0; e < 4; ++e) { b1r[e] = a[e]; b1r[e+4] = b[e]; }
        }
        const int prow = lane & 15;
        #pragma unroll
        for (int mt = 0; mt < 4; ++mt) {
            const f32x4 pt = *(const f32x4*)&pts[mt * 16 + prow][0];
            short8 hv, lv;
            #pragma unroll
            for (int e = 0; e < 8; ++e) {
                float x = fmaf(pt[0], w1r[0][e],
                          fmaf(pt[1], w1r[1][e],
                          fmaf(pt[2], w1r[2][e], b1r[e])));
                x = fmaxf(x, 0.0f);
                const unsigned short hb = f2bf(x);
                hv[e] = (short)hb;
                if (mt == 3) lv[e] = (short)f2bf(x - bf2f(hb));
            }
            *(short8*)&u.ab.ah[((wv * 4 + mt) * 64 + lane) * 8] = hv;
            if (mt == 3) *(short8*)&u.ab.al3[(wv * 64 + lane) * 8] = lv;
        }
    }
    __syncthreads();

    // ---- phase 2: layer 2 GEMM via MFMA ----
    f32x4 acc[4][2];
    #pragma unroll
    for (int mt = 0; mt < 4; ++mt) {
        acc[mt][0] = (f32x4){0.f,0.f,0.f,0.f};
        acc[mt][1] = (f32x4){0.f,0.f,0.f,0.f};
    }
    {
        const int ntg0 = wv * 2, ntg1 = ntg0 + 1;
        const short8* Bh = (const short8*)w2h;
        const short8* Bl = (const short8*)w2l;
        const short8* Ah = (const short8*)u.ab.ah;
        const short8* Al = (const short8*)u.ab.al3;
        __builtin_amdgcn_s_setprio(1);
        #pragma unroll 2
        for (int ks = 0; ks < 8; ++ks) {
            const short8 b0h  = Bh[(ks * 16 + ntg0) * 64 + lane];
            const short8 b0l  = Bl[(ks * 16 + ntg0) * 64 + lane];
            const short8 b1h_ = Bh[(ks * 16 + ntg1) * 64 + lane];
            const short8 b1l_ = Bl[(ks * 16 + ntg1) * 64 + lane];
            #pragma unroll
            for (int mt = 0; mt < 4; ++mt) {
                const short8 ah = Ah[(ks * 4 + mt) * 64 + lane];
                f32x4 c0 = acc[mt][0], c1 = acc[mt][1];
                c0 = mfma16(ah, b0h, c0);
                c0 = mfma16(ah, b0l, c0);
                c1 = mfma16(ah, b1h_, c1);
                c1 = mfma16(ah, b1l_, c1);
                if (mt == 3) {               // rows 48-63: add Al*Bh (3-term)
                    const short8 al = Al[ks * 64 + lane];
                    c0 = mfma16(al, b0h, c0);
                    c1 = mfma16(al, b1h_, c1);
                }
                acc[mt][0] = c0; acc[mt][1] = c1;
            }
        }
        __builtin_amdgcn_s_setprio(0);
    }
    __syncthreads();   // A-frag region dead; safe to overwrite with h2T

    // ---- phase 3: +b2, ReLU; h2 -> bf16 [col][row] stride 72; row 63 f32 ----
    {
        const int ntg0 = wv * 2, ntg1 = ntg0 + 1;
        const int c0 = ntg0 * 16 + (lane & 15);
        const int c1 = ntg1 * 16 + (lane & 15);
        const float b2c0 = b2[c0], b2c1 = b2[c1];
        const int row0b = (lane >> 4) * 4;
        const bool lastGrp = ((lane >> 4) == 3);
        #pragma unroll
        for (int mt = 0; mt < 4; ++mt) {
            const int row0 = mt * 16 + row0b;
            f32x4 v0 = acc[mt][0], v1 = acc[mt][1];
            bf16x4 s0, s1;
            float a0_3 = 0.f, a1_3 = 0.f;
            #pragma unroll
            for (int q = 0; q < 4; ++q) {
                const float a0 = fmaxf(v0[q] + b2c0, 0.0f);
                const float a1 = fmaxf(v1[q] + b2c1, 0.0f);
                s0[q] = f2bf(a0); s1[q] = f2bf(a1);
                if (q == 3) { a0_3 = a0; a1_3 = a1; }
            }
            *(bf16x4*)&u.h2T[c0 * 72 + row0] = s0;
            *(bf16x4*)&u.h2T[c1 * 72 + row0] = s1;
            if (mt == 3 && lastGrp) { row63[c0] = a0_3; row63[c1] = a1_3; }
        }
    }
    __syncthreads();

    // ---- phase 4: layer 3 (f32 VALU). 8 j-groups of 32; all 512 threads. ----
    {
        const int p  = t & 63;          // point (row)
        const int hh = t >> 6;          // j-group 0..7
        f32x4 o = (f32x4){0.f,0.f,0.f,0.f};
        #pragma unroll 4
        for (int jj = 0; jj < 32; ++jj) {
            const int j = hh * 32 + jj;
            const float hv = bf2f(u.h2T[j * 72 + p]);
            const f32x4 w3 = *(const f32x4*)&W3[j * 4];
            o[0] = fmaf(hv, w3[0], o[0]);
            o[1] = fmaf(hv, w3[1], o[1]);
            o[2] = fmaf(hv, w3[2], o[2]);
            o[3] = fmaf(hv, w3[3], o[3]);
        }
        *(f32x4*)&comb[hh][p][0] = o;
    }
    __syncthreads();

    // ---- phase 5: volume rendering (wave 0, lane = sample) ----
    if (t < KS) {
        const int s = t;

        // exact sigma for sample 63: all 64 lanes cooperate on the 256-dot
        float sp = 0.f;
        #pragma unroll
        for (int q = 0; q < 4; ++q) {
            const int j = s * 4 + q;
            sp = fmaf(row63[j], W3[j * 4 + 3], sp);
        }
        #pragma unroll
        for (int off = 32; off > 0; off >>= 1) sp += __shfl_xor(sp, off, 64);
        const float sig63 = sp + b3[3];

        f32x4 oo = (f32x4){0.f,0.f,0.f,0.f};
        #pragma unroll
        for (int q = 0; q < 8; ++q) {
            const f32x4 c = *(const f32x4*)&comb[q][s][0];
            oo[0] += c[0]; oo[1] += c[1]; oo[2] += c[2]; oo[3] += c[3];
        }
        const float o0 = oo[0] + b3[0];
        const float o1 = oo[1] + b3[1];
        const float o2 = oo[2] + b3[2];
        const float sigma = (s == 63) ? sig63 : (oo[3] + b3[3]);

        const float z  = pts[s][3];
        const float zn = __shfl_down(z, 1, 64);
        const float delta = (s == 63) ? 1e10f : (zn - z);
        const float alpha = 1.0f - __expf(-delta * fmaxf(sigma, 0.0f));

        // exclusive product scan of (1 - alpha + eps)
        float P = 1.0f - alpha + 1e-8f;
        #pragma unroll
        for (int off = 1; off < 64; off <<= 1) {
            const float v = __shfl_up(P, off, 64);
            if (s >= off) P *= v;
        }
        float T = __shfl_up(P, 1, 64);
        if (s == 0) T = 1.0f;
        const float w = alpha * T;

        out[(size_t)B * 4 + (size_t)r * 64 + s] = w;

        float ws = w, dep = w * z, q0 = w * o0, q1 = w * o1, q2 = w * o2;
        #pragma unroll
        for (int off = 32; off > 0; off >>= 1) {
            ws  += __shfl_xor(ws,  off, 64);
            dep += __shfl_xor(dep, off, 64);
            q0  += __shfl_xor(q0,  off, 64);
            q1  += __shfl_xor(q1,  off, 64);
            q2  += __shfl_xor(q2,  off, 64);
        }
        if (s == 0) {
            out[(size_t)r * 3 + 0] = q0 + 1.0f - ws;
            out[(size_t)r * 3 + 1] = q1 + 1.0f - ws;
            out[(size_t)r * 3 + 2] = q2 + 1.0f - ws;
            out[(size_t)B * 3 + r] = dep;
            out[(size_t)B * 68 + r] = sig63;
        }
    }
}

extern "C" void kernel_launch(void* const* d_in, const int* in_sizes, int n_in,
                              void* d_out, int out_size, void* d_ws, size_t ws_size,
                              hipStream_t stream)
{
    const int B = in_sizes[0];
    if (ws_size < (size_t)(2 * 65536 * sizeof(unsigned short))) return;  // need 256 KiB

    unsigned short* w2h = (unsigned short*)d_ws;
    unsigned short* w2l = w2h + 65536;

    pack_w2_kernel<<<256, 256, 0, stream>>>((const float*)d_in[6], w2h, w2l);

    nerf_mfma_kernel<<<B, 512, 0, stream>>>(
        (const float*)d_in[0], (const float*)d_in[1],
        (const float*)d_in[2], (const float*)d_in[3],
        (const float*)d_in[4], (const float*)d_in[5],
        (const float*)d_in[7],
        (const float*)d_in[8], (const float*)d_in[9],
        w2h, w2l,
        (float*)d_out, B);
}

// Round 8
// 280.083 us; speedup vs baseline: 12.1682x; 1.1539x over previous
//
#include <hip/hip_runtime.h>
#include <hip/hip_bf16.h>

// NeRF coarse renderer. Layer 2 on bf16 MFMA:
//   rows 0-47:  h2 = Ah*(Bh+Bl)          (2-term, err ~2^-9)
//   rows 48-63: h2 = Ah*(Bh+Bl) + Al*Bh  (3-term — sample 63 feeds the
//                                         alpha = 1-exp(-1e10*relu(sigma)) STEP)
// Layer 3 ALSO on MFMA: wave wv owns h2 cols [wv*32,wv*32+32) = its K-slice;
// phase 3 stores h2 (bf16) in A-frag order, phase 4 = 4 MFMAs vs W3 B-frag
// (cols 0-3 real, 4-15 zero), K-split partials reduced through comb.
// sigma_63 recomputed exactly from an f32-staged post-relu h2 row 63 (f32 W3).
// 1 ray/block, 50 KiB LDS => 3 blocks/CU for cross-block MFMA/VALU overlap.
//
// d_in: 0 near(B,1) 1 far(B,1) 2 center(B,3) 3 dir(B,3)
//       4 W1(3,256) 5 b1(256) 6 W2(256,256) 7 b2(256) 8 W3(256,4) 9 b3(4)
// d_out: [rgb (B,3) | depth (B) | weights (B,64) | sigmas_last (B)] f32
// d_ws: W2 repacked as MFMA B-fragments, bf16 hi[64K] + lo[64K] (256 KiB).

constexpr int H  = 256;
constexpr int KS = 64;     // samples per ray = M rows per block

typedef __attribute__((ext_vector_type(8))) short short8;           // 8 bf16
typedef __attribute__((ext_vector_type(4))) float f32x4;            // C/D frag

__device__ __forceinline__ f32x4 mfma16(short8 a, short8 b, f32x4 c) {
    return __builtin_amdgcn_mfma_f32_16x16x32_bf16(a, b, c, 0, 0, 0);
}
__device__ __forceinline__ void split_bf16(float x, short& hi, short& lo) {
    __hip_bfloat16 h = __float2bfloat16(x);
    float hf = __bfloat162float(h);
    __hip_bfloat16 l = __float2bfloat16(x - hf);
    union { __hip_bfloat16 b; short s; } c1, c2;
    c1.b = h; c2.b = l;
    hi = c1.s; lo = c2.s;
}
__device__ __forceinline__ unsigned short f2bf(float x) {
    union { __hip_bfloat16 b; unsigned short s; } c;
    c.b = __float2bfloat16(x);
    return c.s;
}
__device__ __forceinline__ float bf2f(unsigned short s) {
    union { unsigned int u; float f; } c;
    c.u = ((unsigned int)s) << 16;
    return c.f;
}

// ---- pre-pass: pack W2 (f32 row-major [k][n]) into frag-ordered bf16 hi/lo.
// Element i = ((ks*16 + ntg)*64 + lane)*8 + e  maps to
//   k = ks*32 + (lane>>4)*8 + e,  n = ntg*16 + (lane&15).
__global__ void pack_w2_kernel(const float* __restrict__ W2,
                               unsigned short* __restrict__ hi,
                               unsigned short* __restrict__ lo)
{
    const int i  = blockIdx.x * 256 + threadIdx.x;   // 0..65535
    const int e  = i & 7;
    const int l  = (i >> 3) & 63;
    const int nt = (i >> 9) & 15;
    const int ks = i >> 13;
    const int k  = ks * 32 + (l >> 4) * 8 + e;
    const int n  = nt * 16 + (l & 15);
    short h, lw;
    split_bf16(W2[k * H + n], h, lw);
    hi[i] = (unsigned short)h;
    lo[i] = (unsigned short)lw;
}

// Ah: 8 ks * 4 mt * 64 lanes * 8 = 32 KiB; Al (mt==3 only): 8 ks * 64 * 8 = 8 KiB
struct ABfrags {
    unsigned short ah[8 * 4 * 64 * 8];
    unsigned short al3[8 * 64 * 8];
};
// h2 in A-frag order for layer-3 K-split: [wv][mt][lane][e] = 32 KiB.
union StageU { ABfrags ab; unsigned short h2f[8 * 4 * 64 * 8]; };   // 40 KiB

__launch_bounds__(512, 6)
__global__ void nerf_mfma_kernel(
    const float* __restrict__ g_near, const float* __restrict__ g_far,
    const float* __restrict__ g_center, const float* __restrict__ g_dir,
    const float* __restrict__ W1, const float* __restrict__ b1,
    const float* __restrict__ b2,
    const float* __restrict__ W3, const float* __restrict__ b3,
    const unsigned short* __restrict__ w2h, const unsigned short* __restrict__ w2l,
    float* __restrict__ out, int B)
{
    __shared__ __align__(16) StageU u;             // 40 KiB
    __shared__ __align__(16) float pts[KS][4];     //  1 KiB (px,py,pz,z)
    __shared__ __align__(16) float comb[8][KS][4]; //  8 KiB layer-3 K-partials
    __shared__ __align__(16) float row63[H];       //  1 KiB post-relu f32 h2[63][:]

    const int t    = threadIdx.x;
    const int lane = t & 63;
    const int wv   = __builtin_amdgcn_readfirstlane(t >> 6);   // 0..7
    const int r    = blockIdx.x;                               // ray id

    // ---- phase 0: sample points ----
    if (t < KS) {
        const float nr = g_near[r], fa = g_far[r];
        const float uu = (float)t * (1.0f / 63.0f);
        const float z  = nr * (1.0f - uu) + fa * uu;
        pts[t][0] = g_center[r*3+0] + z * g_dir[r*3+0];
        pts[t][1] = g_center[r*3+1] + z * g_dir[r*3+1];
        pts[t][2] = g_center[r*3+2] + z * g_dir[r*3+2];
        pts[t][3] = z;
    }
    __syncthreads();

    // ---- phase 1: layer 1 (f32); h1 -> bf16 A-frags (hi; +lo for mt==3) ----
    {
        const int kbase = wv * 32 + (lane >> 4) * 8;   // 8 consecutive k
        float w1r[3][8], b1r[8];
        #pragma unroll
        for (int c = 0; c < 3; ++c) {
            const f32x4 a = *(const f32x4*)&W1[c * H + kbase];
            const f32x4 b = *(const f32x4*)&W1[c * H + kbase + 4];
            #pragma unroll
            for (int e = 0; e < 4; ++e) { w1r[c][e] = a[e]; w1r[c][e+4] = b[e]; }
        }
        {
            const f32x4 a = *(const f32x4*)&b1[kbase];
            const f32x4 b = *(const f32x4*)&b1[kbase + 4];
            #pragma unroll
            for (int e = 0; e < 4; ++e) { b1r[e] = a[e]; b1r[e+4] = b[e]; }
        }
        const int prow = lane & 15;
        #pragma unroll
        for (int mt = 0; mt < 4; ++mt) {
            const f32x4 pt = *(const f32x4*)&pts[mt * 16 + prow][0];
            short8 hv, lv;
            #pragma unroll
            for (int e = 0; e < 8; ++e) {
                float x = fmaf(pt[0], w1r[0][e],
                          fmaf(pt[1], w1r[1][e],
                          fmaf(pt[2], w1r[2][e], b1r[e])));
                x = fmaxf(x, 0.0f);
                const unsigned short hb = f2bf(x);
                hv[e] = (short)hb;
                if (mt == 3) lv[e] = (short)f2bf(x - bf2f(hb));
            }
            *(short8*)&u.ab.ah[((wv * 4 + mt) * 64 + lane) * 8] = hv;
            if (mt == 3) *(short8*)&u.ab.al3[(wv * 64 + lane) * 8] = lv;
        }
    }
    __syncthreads();

    // ---- phase 2: layer 2 GEMM via MFMA ----
    f32x4 acc[4][2];
    #pragma unroll
    for (int mt = 0; mt < 4; ++mt) {
        acc[mt][0] = (f32x4){0.f,0.f,0.f,0.f};
        acc[mt][1] = (f32x4){0.f,0.f,0.f,0.f};
    }
    {
        const int ntg0 = wv * 2, ntg1 = ntg0 + 1;
        const short8* Bh = (const short8*)w2h;
        const short8* Bl = (const short8*)w2l;
        const short8* Ah = (const short8*)u.ab.ah;
        const short8* Al = (const short8*)u.ab.al3;
        __builtin_amdgcn_s_setprio(1);
        #pragma unroll 2
        for (int ks = 0; ks < 8; ++ks) {
            const short8 b0h  = Bh[(ks * 16 + ntg0) * 64 + lane];
            const short8 b0l  = Bl[(ks * 16 + ntg0) * 64 + lane];
            const short8 b1h_ = Bh[(ks * 16 + ntg1) * 64 + lane];
            const short8 b1l_ = Bl[(ks * 16 + ntg1) * 64 + lane];
            #pragma unroll
            for (int mt = 0; mt < 4; ++mt) {
                const short8 ah = Ah[(ks * 4 + mt) * 64 + lane];
                f32x4 c0 = acc[mt][0], c1 = acc[mt][1];
                c0 = mfma16(ah, b0h, c0);
                c0 = mfma16(ah, b0l, c0);
                c1 = mfma16(ah, b1h_, c1);
                c1 = mfma16(ah, b1l_, c1);
                if (mt == 3) {               // rows 48-63: add Al*Bh (3-term)
                    const short8 al = Al[ks * 64 + lane];
                    c0 = mfma16(al, b0h, c0);
                    c1 = mfma16(al, b1h_, c1);
                }
                acc[mt][0] = c0; acc[mt][1] = c1;
            }
        }
        __builtin_amdgcn_s_setprio(0);
    }
    __syncthreads();   // A-frag region dead; safe to overwrite with h2f

    // ---- phase 3: +b2, ReLU; h2 -> bf16 A-frag order; row 63 f32 ----
    // Wave wv's acc cols [wv*32, wv*32+32) are its own layer-3 K-slice.
    // Store (row, j): jj = j - wv*32; lane2 = ((jj>>3)<<4)|(row&15); e = jj&7.
    {
        const int c0 = wv * 32 + (lane & 15);
        const int c1 = c0 + 16;
        const float b2c0 = b2[c0], b2c1 = b2[c1];
        const int rlow = (lane >> 4) * 4;
        const int jj0 = lane & 15, jj1 = jj0 + 16;
        const bool lastGrp = ((lane >> 4) == 3);
        #pragma unroll
        for (int mt = 0; mt < 4; ++mt) {
            const f32x4 v0 = acc[mt][0], v1 = acc[mt][1];
            #pragma unroll
            for (int q = 0; q < 4; ++q) {
                const float a0 = fmaxf(v0[q] + b2c0, 0.0f);
                const float a1 = fmaxf(v1[q] + b2c1, 0.0f);
                const int l20 = ((jj0 >> 3) << 4) | (rlow + q);
                const int l21 = ((jj1 >> 3) << 4) | (rlow + q);
                u.h2f[((wv * 4 + mt) * 64 + l20) * 8 + (jj0 & 7)] = f2bf(a0);
                u.h2f[((wv * 4 + mt) * 64 + l21) * 8 + (jj1 & 7)] = f2bf(a1);
                if (mt == 3 && lastGrp && q == 3) { row63[c0] = a0; row63[c1] = a1; }
            }
        }
    }
    __syncthreads();

    // ---- phase 4: layer 3 via MFMA, K-split across waves (k = wv*32..+32) ----
    {
        // W3 B-frag on the fly: k = wv*32 + (lane>>4)*8 + e, n = lane&15 (<4 real)
        const int n = lane & 15;
        short8 bw3;
        #pragma unroll
        for (int e = 0; e < 8; ++e) {
            const int k = wv * 32 + (lane >> 4) * 8 + e;
            const float v = (n < 4) ? W3[k * 4 + n] : 0.0f;
            bw3[e] = (short)f2bf(v);
        }
        const short8* Ah2 = (const short8*)u.h2f;
        #pragma unroll
        for (int mt = 0; mt < 4; ++mt) {
            const short8 a = Ah2[(wv * 4 + mt) * 64 + lane];
            f32x4 d = (f32x4){0.f,0.f,0.f,0.f};
            d = mfma16(a, bw3, d);
            if (n < 4) {
                #pragma unroll
                for (int q = 0; q < 4; ++q)
                    comb[wv][mt * 16 + (lane >> 4) * 4 + q][n] = d[q];
            }
        }
    }
    __syncthreads();

    // ---- phase 5: volume rendering (wave 0, lane = sample) ----
    if (t < KS) {
        const int s = t;

        // exact sigma for sample 63: all 64 lanes cooperate on the 256-dot
        float sp = 0.f;
        #pragma unroll
        for (int q = 0; q < 4; ++q) {
            const int j = s * 4 + q;
            sp = fmaf(row63[j], W3[j * 4 + 3], sp);
        }
        #pragma unroll
        for (int off = 32; off > 0; off >>= 1) sp += __shfl_xor(sp, off, 64);
        const float sig63 = sp + b3[3];

        f32x4 oo = (f32x4){0.f,0.f,0.f,0.f};
        #pragma unroll
        for (int q = 0; q < 8; ++q) {
            const f32x4 c = *(const f32x4*)&comb[q][s][0];
            oo[0] += c[0]; oo[1] += c[1]; oo[2] += c[2]; oo[3] += c[3];
        }
        const float o0 = oo[0] + b3[0];
        const float o1 = oo[1] + b3[1];
        const float o2 = oo[2] + b3[2];
        const float sigma = (s == 63) ? sig63 : (oo[3] + b3[3]);

        const float z  = pts[s][3];
        const float zn = __shfl_down(z, 1, 64);
        const float delta = (s == 63) ? 1e10f : (zn - z);
        const float alpha = 1.0f - __expf(-delta * fmaxf(sigma, 0.0f));

        // exclusive product scan of (1 - alpha + eps)
        float P = 1.0f - alpha + 1e-8f;
        #pragma unroll
        for (int off = 1; off < 64; off <<= 1) {
            const float v = __shfl_up(P, off, 64);
            if (s >= off) P *= v;
        }
        float T = __shfl_up(P, 1, 64);
        if (s == 0) T = 1.0f;
        const float w = alpha * T;

        out[(size_t)B * 4 + (size_t)r * 64 + s] = w;

        float ws = w, dep = w * z, q0 = w * o0, q1 = w * o1, q2 = w * o2;
        #pragma unroll
        for (int off = 32; off > 0; off >>= 1) {
            ws  += __shfl_xor(ws,  off, 64);
            dep += __shfl_xor(dep, off, 64);
            q0  += __shfl_xor(q0,  off, 64);
            q1  += __shfl_xor(q1,  off, 64);
            q2  += __shfl_xor(q2,  off, 64);
        }
        if (s == 0) {
            out[(size_t)r * 3 + 0] = q0 + 1.0f - ws;
            out[(size_t)r * 3 + 1] = q1 + 1.0f - ws;
            out[(size_t)r * 3 + 2] = q2 + 1.0f - ws;
            out[(size_t)B * 3 + r] = dep;
            out[(size_t)B * 68 + r] = sig63;
        }
    }
}

extern "C" void kernel_launch(void* const* d_in, const int* in_sizes, int n_in,
                              void* d_out, int out_size, void* d_ws, size_t ws_size,
                              hipStream_t stream)
{
    const int B = in_sizes[0];
    if (ws_size < (size_t)(2 * 65536 * sizeof(unsigned short))) return;  // need 256 KiB

    unsigned short* w2h = (unsigned short*)d_ws;
    unsigned short* w2l = w2h + 65536;

    pack_w2_kernel<<<256, 256, 0, stream>>>((const float*)d_in[6], w2h, w2l);

    nerf_mfma_kernel<<<B, 512, 0, stream>>>(
        (const float*)d_in[0], (const float*)d_in[1],
        (const float*)d_in[2], (const float*)d_in[3],
        (const float*)d_in[4], (const float*)d_in[5],
        (const float*)d_in[7],
        (const float*)d_in[8], (const float*)d_in[9],
        w2h, w2l,
        (float*)d_out, B);
}